// Round 4
// baseline (257.994 us; speedup 1.0000x reference)
//
#include <hip/hip_runtime.h>

#define NTOK   2048
#define DIM    512
#define FDIM   2048
#define NEXP   16
#define CAP    768     // max routed tokens buffered per expert (mean ~256)
#define BT2    128     // token block per K2 workgroup
#define NTB    (CAP / BT2)   // 6 token-block slots

typedef __bf16 bf16x8 __attribute__((ext_vector_type(8)));
typedef __bf16 bf16x4 __attribute__((ext_vector_type(4)));
typedef float  floatx4 __attribute__((ext_vector_type(4)));

// workspace layout (bytes)
#define WS_COUNTS    0         // 16 ints (memset 0)
#define WS_ZEROPAGE  1024      // >=1KB zeros for pad-lane loads (memset 0)
#define WS_TOPIDX    4096      // NTOK*2 ints
#define WS_ROUTW     20480     // NTOK*2 floats
#define WS_HMEAN     36864     // NEXP*FDIM floats (memset 0 — atomic accumulated)
#define WS_YMEAN     167936    // NEXP*DIM floats
#define WS_XG        200704    // NEXP*CAP*DIM bf16 = 12.6 MB
#define WS_ZERO_BYTES 167936   // counts + zero page + hmean

__device__ __forceinline__ void async_lds16(const void* g, void* l) {
    __builtin_amdgcn_global_load_lds(
        (__attribute__((address_space(1))) void*)(void*)g,
        (__attribute__((address_space(3))) void*)l, 16, 0, 0);
}

// ---------------- K1: gate logits, top-2 softmax, gather x rows (bf16) ------
__global__ __launch_bounds__(256) void k1_route_gather(
    const float* __restrict__ x, const float* __restrict__ gw,
    int* __restrict__ counts, int* __restrict__ top_idx,
    float* __restrict__ routw, __bf16* __restrict__ Xg)
{
    __shared__ float xt[16 * DIM];    // 32 KB: 16 token rows
    __shared__ float lg[16][17];
    __shared__ int   gdst[16][2];
    const int tid = threadIdx.x;
    const int t0  = blockIdx.x * 16;

    {   // stage 16 token rows, coalesced float4
        const float4* src = (const float4*)(x + (size_t)t0 * DIM);
        float4* dst = (float4*)xt;
        #pragma unroll
        for (int i = 0; i < 8; ++i) dst[i * 256 + tid] = src[i * 256 + tid];
    }
    __syncthreads();

    {   // logits: thread = (token tl, expert e)
        const int tl = tid >> 4, e = tid & 15;
        const float4* xr = (const float4*)(xt + tl * DIM);
        const float4* gr = (const float4*)(gw + e * DIM);
        float acc = 0.f;
        #pragma unroll 8
        for (int j = 0; j < DIM / 4; ++j) {
            float4 a = xr[j], b = gr[j];
            acc += a.x * b.x + a.y * b.y + a.z * b.z + a.w * b.w;
        }
        lg[tl][e] = acc;
    }
    __syncthreads();

    if (tid < 16) {   // per-token top-2 + softmax + slot allocation
        const int tl = tid;
        float v0 = -1e30f, v1 = -1e30f; int i0 = 0, i1 = 0;
        #pragma unroll
        for (int e = 0; e < NEXP; ++e) {
            float v = lg[tl][e];
            if (v > v0)      { v1 = v0; i1 = i0; v0 = v; i0 = e; }
            else if (v > v1) { v1 = v;  i1 = e; }
        }
        float e1 = __expf(v1 - v0);          // v0 >= v1
        float w0 = 1.f / (1.f + e1);
        float w1 = 1.f - w0;
        const int t = t0 + tl;
        top_idx[t * 2]     = i0; top_idx[t * 2 + 1] = i1;
        routw[t * 2]       = w0; routw[t * 2 + 1]   = w1;
        int p0 = atomicAdd(counts + i0, 1);
        int p1 = atomicAdd(counts + i1, 1);
        gdst[tl][0] = (p0 < CAP) ? (i0 * CAP + p0) : -1;
        gdst[tl][1] = (p1 < CAP) ? (i1 * CAP + p1) : -1;
    }
    __syncthreads();

    // gather-write 32 rows (16 tokens x 2 experts) as bf16, 8B stores
    #pragma unroll
    for (int it = 0; it < 16; ++it) {
        int s   = it * 256 + tid;          // 0..4095
        int job = s >> 7, el = s & 127;    // job: (token,k), el: float4 index
        int tl  = job >> 1, k = job & 1;
        int dst = gdst[tl][k];
        if (dst >= 0) {
            float4 v = ((const float4*)(xt + tl * DIM))[el];
            bf16x4 o = { (__bf16)v.x, (__bf16)v.y, (__bf16)v.z, (__bf16)v.w };
            *(bf16x4*)(Xg + (size_t)dst * DIM + el * 4) = o;
        }
    }
}

// ---------------- K2: per (expert, 64-f-tile, 128-token-block) --------------
// A-operand (W1) goes global -> regs -> cvt -> MFMA directly: lane (q,l15)'s
// fragment is 32B CONTIGUOUS in row-major W1; a wave's paired loads cover
// 16 rows x 128B full lines (perfect byte efficiency). Issued one chunk ahead
// (T14), cvt after the MFMAs -- no barrier governs A. Only X lives in LDS
// (double-buffered, global_load_lds, 33 KB total -> 4 blocks/CU) with ONE
// barrier per chunk. bid = xcd + 8*(tb + 6*tgrp): all token-blocks of a
// (e,f0) tile land on one XCD so W1 crosses HBM once.
__global__ __launch_bounds__(256) void k2_expert_ffn(
    const float* __restrict__ w1, const __bf16* __restrict__ Xg,
    const int* __restrict__ counts, const __bf16* __restrict__ zp,
    float* __restrict__ hmean)
{
    __shared__ __align__(16) __bf16 xs[2][8 * 128 * 8];   // 2 x 16 KB [kg][t][8] linear
    __shared__ float hred[64][2];

    const int tid  = threadIdx.x;
    const int bid  = blockIdx.x;
    const int xcd  = bid & 7;
    const int rest = bid >> 3;           // 0..383
    const int tb   = rest % NTB;
    const int tgrp = rest / NTB;         // 0..63
    const int tile = tgrp * 8 + xcd;     // 0..511
    const int e    = tile & 15;
    const int f0   = (tile >> 4) * 64;
    const int cnt  = min(counts[e], CAP);
    if (tb * BT2 >= cnt) return;         // inactive slot
    const float inv = 1.f / (float)cnt;

    const int wv   = tid >> 6;
    const int lane = tid & 63;
    const int q    = lane >> 4;          // mfma quad
    const int l15  = lane & 15;
    const int fsub = (wv & 1) * 32;
    const int tsub = (wv >> 1) * 64;

    // per-thread W1 row bases for the two A-fragment rows (fa=0,1)
    const float* arow0 = w1 + ((size_t)(e * FDIM + f0 + fsub + l15)) * DIM + q * 8;
    const float* arow1 = arow0 + 16 * DIM;

    float4 aw[8];        // in-flight fp32 A data for the NEXT chunk
    bf16x8 A[2][2];      // current chunk's A-frags [ks][fa]

    // issue chunk c's A loads (held in regs across this chunk's MFMAs)
    auto ISSUE_A = [&](int c) {
        const float* p0 = arow0 + c * 64;         // ks=0: d-group base
        const float* p1 = arow1 + c * 64;
        aw[0] = ((const float4*)p0)[0];       aw[1] = ((const float4*)p0)[1];
        aw[2] = ((const float4*)p1)[0];       aw[3] = ((const float4*)p1)[1];
        aw[4] = ((const float4*)(p0 + 32))[0]; aw[5] = ((const float4*)(p0 + 32))[1];
        aw[6] = ((const float4*)(p1 + 32))[0]; aw[7] = ((const float4*)(p1 + 32))[1];
    };
    // convert in-flight fp32 -> bf16 frags (compiler's vmcnt wait lands here)
    auto CVT_A = [&]() {
        #pragma unroll
        for (int i = 0; i < 4; ++i) {
            float4 a = aw[i * 2], b = aw[i * 2 + 1];
            bf16x8 v;
            v[0] = (__bf16)a.x; v[1] = (__bf16)a.y; v[2] = (__bf16)a.z; v[3] = (__bf16)a.w;
            v[4] = (__bf16)b.x; v[5] = (__bf16)b.y; v[6] = (__bf16)b.z; v[7] = (__bf16)b.w;
            A[i >> 1][i & 1] = v;     // i: 0=ks0fa0 1=ks0fa1 2=ks1fa0 3=ks1fa1
        }
    };
    // X chunk c -> buffer b, direct global->LDS (wave-uniform dest + lane*16)
    auto STAGE_X = [&](int b, int c) {
        __bf16* dst0 = &xs[b][0];
        #pragma unroll
        for (int it = 0; it < 4; ++it) {
            int base = it * 256 + wv * 64;          // wave-uniform 16B-slot base
            int slot = base + lane;                 // slot = kg*128 + t
            int kg = slot >> 7, t = slot & 127;
            int r  = tb * BT2 + t;
            const __bf16* src = (r < cnt)
                ? (Xg + ((size_t)(e * CAP + r)) * DIM + c * 64 + kg * 8)
                : zp;                               // pad rows read zero page
            async_lds16(src, dst0 + (size_t)base * 8);
        }
    };

    // prologue: chunk 0 in flight
    ISSUE_A(0);
    STAGE_X(0, 0);
    CVT_A();
    __syncthreads();                     // X buffer 0 ready

    floatx4 acc[2][4];
    #pragma unroll
    for (int a = 0; a < 2; ++a)
        #pragma unroll
        for (int b = 0; b < 4; ++b) acc[a][b] = (floatx4)0.f;

    #pragma unroll
    for (int c = 0; c < 8; ++c) {        // K chunks of 64
        if (c < 7) {                     // issue next chunk (A regs + X async)
            ISSUE_A(c + 1);
            STAGE_X((c + 1) & 1, c + 1);
        }
        const __bf16* xp = &xs[c & 1][0];
        #pragma unroll
        for (int ks = 0; ks < 2; ++ks) {
            const int kg = ks * 4 + q;
            #pragma unroll
            for (int tt = 0; tt < 4; ++tt) {
                bf16x8 bfr = *(const bf16x8*)(xp + ((size_t)kg * 128 + tsub + tt * 16 + l15) * 8);
                acc[0][tt] = __builtin_amdgcn_mfma_f32_16x16x32_bf16(A[ks][0], bfr, acc[0][tt], 0, 0, 0);
                acc[1][tt] = __builtin_amdgcn_mfma_f32_16x16x32_bf16(A[ks][1], bfr, acc[1][tt], 0, 0, 0);
            }
        }
        if (c < 7) {
            CVT_A();                     // A loads landed during the MFMAs
            __syncthreads();             // next X buffer ready
        }
    }

    // silu then column-sum (pad cols give silu(0)=0)
    float hs[8];
    #pragma unroll
    for (int i = 0; i < 8; ++i) hs[i] = 0.f;
    #pragma unroll
    for (int fa = 0; fa < 2; ++fa)
        #pragma unroll
        for (int tt = 0; tt < 4; ++tt)
            #pragma unroll
            for (int r = 0; r < 4; ++r) {
                float v = acc[fa][tt][r];
                hs[fa * 4 + r] += v / (1.f + __expf(-v));
            }

    // sum over the 16 token-columns held across lanes of each quad
    #pragma unroll
    for (int i = 0; i < 8; ++i) {
        float v = hs[i];
        v += __shfl_xor(v, 1);
        v += __shfl_xor(v, 2);
        v += __shfl_xor(v, 4);
        v += __shfl_xor(v, 8);
        hs[i] = v;
    }
    if (l15 == 0) {
        #pragma unroll
        for (int fa = 0; fa < 2; ++fa)
            #pragma unroll
            for (int r = 0; r < 4; ++r) {
                int row = fsub + fa * 16 + q * 4 + r;
                hred[row][wv >> 1] = hs[fa * 4 + r];
            }
    }
    __syncthreads();
    if (tid < 64)
        atomicAdd(hmean + (size_t)e * FDIM + f0 + tid,
                  (hred[tid][0] + hred[tid][1]) * inv);
}

// ---------------- K3: y_mean[e,d] = h_mean[e,:] . w2[e,d,:]  (fp32) ---------
__global__ __launch_bounds__(256) void k3_ymean(
    const float* __restrict__ w2, const float* __restrict__ hmean,
    const int* __restrict__ counts, float* __restrict__ ymean)
{
    __shared__ float hl[FDIM];           // 8 KB
    const int tid = threadIdx.x;
    const int bid = blockIdx.x;
    const int e   = bid >> 7;
    const int d0  = (bid & 127) * 4;

    {
        const float4* hg = (const float4*)(hmean + (size_t)e * FDIM);
        float4* hl4 = (float4*)hl;
        hl4[tid]       = hg[tid];
        hl4[256 + tid] = hg[256 + tid];
    }
    __syncthreads();

    const int wv = tid >> 6, lane = tid & 63;
    const int d = d0 + wv;
    const float4* wr  = (const float4*)(w2 + ((size_t)e * DIM + d) * FDIM);
    const float4* hl4 = (const float4*)hl;
    float acc = 0.f;
    #pragma unroll
    for (int i = 0; i < 8; ++i) {
        float4 a = wr[i * 64 + lane];
        float4 h = hl4[i * 64 + lane];
        acc += a.x * h.x + a.y * h.y + a.z * h.z + a.w * h.w;
    }
    #pragma unroll
    for (int m = 1; m < 64; m <<= 1) acc += __shfl_xor(acc, m);
    if (lane == 0)
        ymean[e * DIM + d] = (counts[e] > 0) ? acc : 0.f;
}

// ---------------- K4: out[t,:] = w0*y[e0,:] + w1*y[e1,:] --------------------
__global__ __launch_bounds__(256) void k4_combine(
    const int* __restrict__ top_idx, const float* __restrict__ routw,
    const float* __restrict__ ymean, float* __restrict__ out)
{
    const int idx = blockIdx.x * 256 + threadIdx.x;   // float4 index
    const int t = idx >> 7;
    const int c = idx & 127;
    const int i0 = top_idx[t * 2], i1 = top_idx[t * 2 + 1];
    const float w0 = routw[t * 2], w1 = routw[t * 2 + 1];
    float4 a = ((const float4*)(ymean + (size_t)i0 * DIM))[c];
    float4 b = ((const float4*)(ymean + (size_t)i1 * DIM))[c];
    float4 o;
    o.x = w0 * a.x + w1 * b.x;
    o.y = w0 * a.y + w1 * b.y;
    o.z = w0 * a.z + w1 * b.z;
    o.w = w0 * a.w + w1 * b.w;
    ((float4*)out)[idx] = o;
}

extern "C" void kernel_launch(void* const* d_in, const int* in_sizes, int n_in,
                              void* d_out, int out_size, void* d_ws, size_t ws_size,
                              hipStream_t stream)
{
    (void)in_sizes; (void)n_in; (void)out_size; (void)ws_size;
    const float* x  = (const float*)d_in[0];   // [4,512,512]
    const float* gw = (const float*)d_in[1];   // [16,512]
    const float* w1 = (const float*)d_in[2];   // [16,2048,512]
    const float* w2 = (const float*)d_in[3];   // [16,512,2048]
    float* out = (float*)d_out;

    char* ws = (char*)d_ws;
    int*    counts  = (int*)   (ws + WS_COUNTS);
    const __bf16* zp = (const __bf16*)(ws + WS_ZEROPAGE);
    int*    top_idx = (int*)   (ws + WS_TOPIDX);
    float*  routw   = (float*) (ws + WS_ROUTW);
    float*  hmean   = (float*) (ws + WS_HMEAN);
    float*  ymean   = (float*) (ws + WS_YMEAN);
    __bf16* Xg      = (__bf16*)(ws + WS_XG);

    hipMemsetAsync(d_ws, 0, WS_ZERO_BYTES, stream);   // counts + zero page + hmean

    k1_route_gather<<<dim3(NTOK / 16), dim3(256), 0, stream>>>(x, gw, counts, top_idx, routw, Xg);
    k2_expert_ffn  <<<dim3(NTB * 32 * NEXP), dim3(256), 0, stream>>>(w1, Xg, counts, zp, hmean);
    k3_ymean       <<<dim3(NEXP * 128), dim3(256), 0, stream>>>(w2, hmean, counts, ymean);
    k4_combine     <<<dim3(NTOK * DIM / 4 / 256), dim3(256), 0, stream>>>(top_idx, routw, ymean, out);
}

// Round 5
// 217.570 us; speedup vs baseline: 1.1858x; 1.1858x over previous
//
#include <hip/hip_runtime.h>

#define NTOK   2048
#define DIM    512
#define FDIM   2048
#define NEXP   16
#define CAP    768     // max routed tokens buffered per expert (mean ~256)
#define BT2    128     // token block per K2 workgroup
#define NTB    (CAP / BT2)   // 6 token-block slots

typedef __bf16 bf16x8 __attribute__((ext_vector_type(8)));
typedef __bf16 bf16x4 __attribute__((ext_vector_type(4)));
typedef float  floatx4 __attribute__((ext_vector_type(4)));

// workspace layout (bytes)
#define WS_COUNTS    0         // 16 ints (memset 0)
#define WS_ZEROPAGE  1024      // >=1KB zeros for pad-lane loads (memset 0)
#define WS_TOPIDX    4096      // NTOK*2 ints
#define WS_ROUTW     20480     // NTOK*2 floats
#define WS_HMEAN     36864     // NEXP*FDIM floats (memset 0 — atomic accumulated)
#define WS_YMEAN     167936    // NEXP*DIM floats
#define WS_XG        200704    // NEXP*CAP*DIM bf16 = 12.6 MB
#define WS_ZERO_BYTES 167936   // counts + zero page + hmean

__device__ __forceinline__ void async_lds16(const void* g, void* l) {
    __builtin_amdgcn_global_load_lds(
        (__attribute__((address_space(1))) void*)(void*)g,
        (__attribute__((address_space(3))) void*)l, 16, 0, 0);
}

// ---------------- K1: gate logits, top-2 softmax, gather x rows (bf16) ------
__global__ __launch_bounds__(256) void k1_route_gather(
    const float* __restrict__ x, const float* __restrict__ gw,
    int* __restrict__ counts, int* __restrict__ top_idx,
    float* __restrict__ routw, __bf16* __restrict__ Xg)
{
    __shared__ float xt[16 * DIM];    // 32 KB: 16 token rows
    __shared__ float lg[16][17];
    __shared__ int   gdst[16][2];
    const int tid = threadIdx.x;
    const int t0  = blockIdx.x * 16;

    {   // stage 16 token rows, coalesced float4
        const float4* src = (const float4*)(x + (size_t)t0 * DIM);
        float4* dst = (float4*)xt;
        #pragma unroll
        for (int i = 0; i < 8; ++i) dst[i * 256 + tid] = src[i * 256 + tid];
    }
    __syncthreads();

    {   // logits: thread = (token tl, expert e)
        const int tl = tid >> 4, e = tid & 15;
        const float4* xr = (const float4*)(xt + tl * DIM);
        const float4* gr = (const float4*)(gw + e * DIM);
        float acc = 0.f;
        #pragma unroll 8
        for (int j = 0; j < DIM / 4; ++j) {
            float4 a = xr[j], b = gr[j];
            acc += a.x * b.x + a.y * b.y + a.z * b.z + a.w * b.w;
        }
        lg[tl][e] = acc;
    }
    __syncthreads();

    if (tid < 16) {   // per-token top-2 + softmax + slot allocation
        const int tl = tid;
        float v0 = -1e30f, v1 = -1e30f; int i0 = 0, i1 = 0;
        #pragma unroll
        for (int e = 0; e < NEXP; ++e) {
            float v = lg[tl][e];
            if (v > v0)      { v1 = v0; i1 = i0; v0 = v; i0 = e; }
            else if (v > v1) { v1 = v;  i1 = e; }
        }
        float e1 = __expf(v1 - v0);          // v0 >= v1
        float w0 = 1.f / (1.f + e1);
        float w1 = 1.f - w0;
        const int t = t0 + tl;
        top_idx[t * 2]     = i0; top_idx[t * 2 + 1] = i1;
        routw[t * 2]       = w0; routw[t * 2 + 1]   = w1;
        int p0 = atomicAdd(counts + i0, 1);
        int p1 = atomicAdd(counts + i1, 1);
        gdst[tl][0] = (p0 < CAP) ? (i0 * CAP + p0) : -1;
        gdst[tl][1] = (p1 < CAP) ? (i1 * CAP + p1) : -1;
    }
    __syncthreads();

    // gather-write 32 rows (16 tokens x 2 experts) as bf16, 8B stores
    #pragma unroll
    for (int it = 0; it < 16; ++it) {
        int s   = it * 256 + tid;          // 0..4095
        int job = s >> 7, el = s & 127;    // job: (token,k), el: float4 index
        int tl  = job >> 1, k = job & 1;
        int dst = gdst[tl][k];
        if (dst >= 0) {
            float4 v = ((const float4*)(xt + tl * DIM))[el];
            bf16x4 o = { (__bf16)v.x, (__bf16)v.y, (__bf16)v.z, (__bf16)v.w };
            *(bf16x4*)(Xg + (size_t)dst * DIM + el * 4) = o;
        }
    }
}

// ---------------- K2: per (expert, 64-f-tile, 128-token-block) --------------
// R0 structure (46 us measured: grid 6x32x16, FT=64, BT=128, 2 barriers/chunk,
// 6 blocks/CU) with ONE change: X staging goes through global_load_lds
// (direct-to-LDS DMA, linear [kg][128][8] layout) instead of the
// global->VGPR->ds_write path into the padded [kg][129][8] layout.
// R4 measured this X path at SQ_LDS_BANK_CONFLICT = 0; removes 4 global
// loads + 4 ds_writes per thread per chunk from the VALU/LDS critical path.
__global__ __launch_bounds__(256) void k2_expert_ffn(
    const float* __restrict__ w1, const __bf16* __restrict__ Xg,
    const int* __restrict__ counts, const __bf16* __restrict__ zp,
    float* __restrict__ hmean)
{
    __shared__ __align__(16) __bf16 w1s[8 * 65 * 8];    // 8.3 KB [kg][f(+pad)][8]
    __shared__ __align__(16) __bf16 xs[8 * 128 * 8];    // 16 KB  [kg][t][8] linear
    __shared__ float hred[64][2];

    const int tid = threadIdx.x;
    const int bid = blockIdx.x;
    const int tb  = bid >> 9;            // slow: token-block (same (e,f) tiles 512 apart -> same XCD)
    const int rem = bid & 511;
    const int e   = rem & 15;            // expert fast
    const int f0  = (rem >> 4) * 64;
    const int cnt = min(counts[e], CAP);
    if (tb * BT2 >= cnt) return;         // inactive slot
    const float inv = 1.f / (float)cnt;

    const int wv   = tid >> 6;
    const int lane = tid & 63;
    const int q    = lane >> 4;          // mfma quad
    const int l15  = lane & 15;
    const int fsub = (wv & 1) * 32;
    const int tsub = (wv >> 1) * 64;

    floatx4 acc[2][4];
    #pragma unroll
    for (int a = 0; a < 2; ++a)
        #pragma unroll
        for (int b = 0; b < 4; ++b) acc[a][b] = (floatx4)0.f;

    for (int c = 0; c < 8; ++c) {        // K chunks of 64
        const int d0 = c * 64;
        __syncthreads();
        // stage X chunk FIRST (async DMA overlaps the W1 load+cvt+write below):
        // 128 t x 64 d bf16, direct global->LDS, wave-uniform dest + lane*16
        {
            #pragma unroll
            for (int it = 0; it < 4; ++it) {
                int base = it * 256 + wv * 64;      // wave-uniform 16B-slot base
                int slot = base + lane;             // slot = kg*128 + t
                int kg = slot >> 7, t = slot & 127;
                int r  = tb * BT2 + t;
                const __bf16* src = (r < cnt)
                    ? (Xg + ((size_t)(e * CAP + r)) * DIM + d0 + kg * 8)
                    : zp;                           // pad rows read zero page
                async_lds16(src, xs + (size_t)base * 8);
            }
        }
        // stage W1 tile chunk: 64 f x 64 d, fp32 -> bf16
        #pragma unroll
        for (int it = 0; it < 2; ++it) {
            int s = it * 256 + tid;
            int f = s >> 3, g = s & 7;
            const float* src = w1 + ((size_t)(e * FDIM + f0 + f)) * DIM + d0 + g * 8;
            float4 a = ((const float4*)src)[0];
            float4 b = ((const float4*)src)[1];
            bf16x8 v;
            v[0] = (__bf16)a.x; v[1] = (__bf16)a.y; v[2] = (__bf16)a.z; v[3] = (__bf16)a.w;
            v[4] = (__bf16)b.x; v[5] = (__bf16)b.y; v[6] = (__bf16)b.z; v[7] = (__bf16)b.w;
            *(bf16x8*)(w1s + ((size_t)g * 65 + f) * 8) = v;
        }
        __syncthreads();                 // drains X DMA (vmcnt) + W1 writes (lgkm)
        // 2 K-steps of 32 per chunk
        #pragma unroll
        for (int ks = 0; ks < 2; ++ks) {
            const int kg = ks * 4 + q;
            bf16x8 af0 = *(const bf16x8*)(w1s + (kg * 65 + fsub + l15) * 8);
            bf16x8 af1 = *(const bf16x8*)(w1s + (kg * 65 + fsub + 16 + l15) * 8);
            #pragma unroll
            for (int tt = 0; tt < 4; ++tt) {
                bf16x8 bfr = *(const bf16x8*)(xs + (kg * 128 + tsub + tt * 16 + l15) * 8);
                acc[0][tt] = __builtin_amdgcn_mfma_f32_16x16x32_bf16(af0, bfr, acc[0][tt], 0, 0, 0);
                acc[1][tt] = __builtin_amdgcn_mfma_f32_16x16x32_bf16(af1, bfr, acc[1][tt], 0, 0, 0);
            }
        }
    }

    // silu then column-sum (pad cols give silu(0)=0)
    float hs[8];
    #pragma unroll
    for (int i = 0; i < 8; ++i) hs[i] = 0.f;
    #pragma unroll
    for (int fa = 0; fa < 2; ++fa)
        #pragma unroll
        for (int tt = 0; tt < 4; ++tt)
            #pragma unroll
            for (int r = 0; r < 4; ++r) {
                float v = acc[fa][tt][r];
                hs[fa * 4 + r] += v / (1.f + __expf(-v));
            }

    // sum over the 16 token-columns held across lanes of each quad
    #pragma unroll
    for (int i = 0; i < 8; ++i) {
        float v = hs[i];
        v += __shfl_xor(v, 1);
        v += __shfl_xor(v, 2);
        v += __shfl_xor(v, 4);
        v += __shfl_xor(v, 8);
        hs[i] = v;
    }
    if (l15 == 0) {
        #pragma unroll
        for (int fa = 0; fa < 2; ++fa)
            #pragma unroll
            for (int r = 0; r < 4; ++r) {
                int row = fsub + fa * 16 + q * 4 + r;
                hred[row][wv >> 1] = hs[fa * 4 + r];
            }
    }
    __syncthreads();
    if (tid < 64)
        atomicAdd(hmean + (size_t)e * FDIM + f0 + tid,
                  (hred[tid][0] + hred[tid][1]) * inv);
}

// ---------------- K3: y_mean[e,d] = h_mean[e,:] . w2[e,d,:]  (fp32) ---------
__global__ __launch_bounds__(256) void k3_ymean(
    const float* __restrict__ w2, const float* __restrict__ hmean,
    const int* __restrict__ counts, float* __restrict__ ymean)
{
    __shared__ float hl[FDIM];           // 8 KB
    const int tid = threadIdx.x;
    const int bid = blockIdx.x;
    const int e   = bid >> 7;
    const int d0  = (bid & 127) * 4;

    {
        const float4* hg = (const float4*)(hmean + (size_t)e * FDIM);
        float4* hl4 = (float4*)hl;
        hl4[tid]       = hg[tid];
        hl4[256 + tid] = hg[256 + tid];
    }
    __syncthreads();

    const int wv = tid >> 6, lane = tid & 63;
    const int d = d0 + wv;
    const float4* wr  = (const float4*)(w2 + ((size_t)e * DIM + d) * FDIM);
    const float4* hl4 = (const float4*)hl;
    float acc = 0.f;
    #pragma unroll
    for (int i = 0; i < 8; ++i) {
        float4 a = wr[i * 64 + lane];
        float4 h = hl4[i * 64 + lane];
        acc += a.x * h.x + a.y * h.y + a.z * h.z + a.w * h.w;
    }
    #pragma unroll
    for (int m = 1; m < 64; m <<= 1) acc += __shfl_xor(acc, m);
    if (lane == 0)
        ymean[e * DIM + d] = (counts[e] > 0) ? acc : 0.f;
}

// ---------------- K4: out[t,:] = w0*y[e0,:] + w1*y[e1,:] --------------------
__global__ __launch_bounds__(256) void k4_combine(
    const int* __restrict__ top_idx, const float* __restrict__ routw,
    const float* __restrict__ ymean, float* __restrict__ out)
{
    const int idx = blockIdx.x * 256 + threadIdx.x;   // float4 index
    const int t = idx >> 7;
    const int c = idx & 127;
    const int i0 = top_idx[t * 2], i1 = top_idx[t * 2 + 1];
    const float w0 = routw[t * 2], w1 = routw[t * 2 + 1];
    float4 a = ((const float4*)(ymean + (size_t)i0 * DIM))[c];
    float4 b = ((const float4*)(ymean + (size_t)i1 * DIM))[c];
    float4 o;
    o.x = w0 * a.x + w1 * b.x;
    o.y = w0 * a.y + w1 * b.y;
    o.z = w0 * a.z + w1 * b.z;
    o.w = w0 * a.w + w1 * b.w;
    ((float4*)out)[idx] = o;
}

extern "C" void kernel_launch(void* const* d_in, const int* in_sizes, int n_in,
                              void* d_out, int out_size, void* d_ws, size_t ws_size,
                              hipStream_t stream)
{
    (void)in_sizes; (void)n_in; (void)out_size; (void)ws_size;
    const float* x  = (const float*)d_in[0];   // [4,512,512]
    const float* gw = (const float*)d_in[1];   // [16,512]
    const float* w1 = (const float*)d_in[2];   // [16,2048,512]
    const float* w2 = (const float*)d_in[3];   // [16,512,2048]
    float* out = (float*)d_out;

    char* ws = (char*)d_ws;
    int*    counts  = (int*)   (ws + WS_COUNTS);
    const __bf16* zp = (const __bf16*)(ws + WS_ZEROPAGE);
    int*    top_idx = (int*)   (ws + WS_TOPIDX);
    float*  routw   = (float*) (ws + WS_ROUTW);
    float*  hmean   = (float*) (ws + WS_HMEAN);
    float*  ymean   = (float*) (ws + WS_YMEAN);
    __bf16* Xg      = (__bf16*)(ws + WS_XG);

    hipMemsetAsync(d_ws, 0, WS_ZERO_BYTES, stream);   // counts + zero page + hmean

    k1_route_gather<<<dim3(NTOK / 16), dim3(256), 0, stream>>>(x, gw, counts, top_idx, routw, Xg);
    k2_expert_ffn  <<<dim3(NTB * 32 * NEXP), dim3(256), 0, stream>>>(w1, Xg, counts, zp, hmean);
    k3_ymean       <<<dim3(NEXP * 128), dim3(256), 0, stream>>>(w2, hmean, counts, ymean);
    k4_combine     <<<dim3(NTOK * DIM / 4 / 256), dim3(256), 0, stream>>>(top_idx, routw, ymean, out);
}

// Round 6
// 217.470 us; speedup vs baseline: 1.1863x; 1.0005x over previous
//
#include <hip/hip_runtime.h>

#define NTOK   2048
#define DIM    512
#define FDIM   2048
#define NEXP   16
#define CAP    768     // max routed tokens buffered per expert (mean ~256)
#define BT2    128     // token block per K2 tb-slot
#define NTB    (CAP / BT2)   // 6 token-block slots

typedef __bf16 bf16x8 __attribute__((ext_vector_type(8)));
typedef __bf16 bf16x4 __attribute__((ext_vector_type(4)));
typedef float  floatx4 __attribute__((ext_vector_type(4)));

// workspace layout (bytes)
#define WS_COUNTS    0         // 16 ints (memset 0)
#define WS_ZEROPAGE  1024      // >=1KB zeros for pad-lane loads (memset 0)
#define WS_TOPIDX    4096      // NTOK*2 ints
#define WS_ROUTW     20480     // NTOK*2 floats
#define WS_HMEAN     36864     // NEXP*FDIM floats (zeroed by k1 — atomic accumulated by k2)
#define WS_YMEAN     167936    // NEXP*DIM floats
#define WS_XG        200704    // NEXP*CAP*DIM bf16 = 12.6 MB
#define WS_ZERO_BYTES 2048     // counts + zero page only

// ---------------- K1: gate logits, top-2 softmax, gather x rows (bf16) ------
__global__ __launch_bounds__(256) void k1_route_gather(
    const float* __restrict__ x, const float* __restrict__ gw,
    int* __restrict__ counts, int* __restrict__ top_idx,
    float* __restrict__ routw, __bf16* __restrict__ Xg,
    float* __restrict__ hmean)
{
    __shared__ float xt[16 * DIM];    // 32 KB: 16 token rows
    __shared__ float lg[16][17];
    __shared__ int   gdst[16][2];
    const int tid = threadIdx.x;
    const int t0  = blockIdx.x * 16;

    // zero this block's slice of hmean (32768 floats over 128 blocks x 256 thr)
    hmean[blockIdx.x * 256 + tid] = 0.f;

    {   // stage 16 token rows, coalesced float4
        const float4* src = (const float4*)(x + (size_t)t0 * DIM);
        float4* dst = (float4*)xt;
        #pragma unroll
        for (int i = 0; i < 8; ++i) dst[i * 256 + tid] = src[i * 256 + tid];
    }
    __syncthreads();

    {   // logits: thread = (token tl, expert e)
        const int tl = tid >> 4, e = tid & 15;
        const float4* xr = (const float4*)(xt + tl * DIM);
        const float4* gr = (const float4*)(gw + e * DIM);
        float acc = 0.f;
        #pragma unroll 8
        for (int j = 0; j < DIM / 4; ++j) {
            float4 a = xr[j], b = gr[j];
            acc += a.x * b.x + a.y * b.y + a.z * b.z + a.w * b.w;
        }
        lg[tl][e] = acc;
    }
    __syncthreads();

    if (tid < 16) {   // per-token top-2 + softmax + slot allocation
        const int tl = tid;
        float v0 = -1e30f, v1 = -1e30f; int i0 = 0, i1 = 0;
        #pragma unroll
        for (int e = 0; e < NEXP; ++e) {
            float v = lg[tl][e];
            if (v > v0)      { v1 = v0; i1 = i0; v0 = v; i0 = e; }
            else if (v > v1) { v1 = v;  i1 = e; }
        }
        float e1 = __expf(v1 - v0);          // v0 >= v1
        float w0 = 1.f / (1.f + e1);
        float w1 = 1.f - w0;
        const int t = t0 + tl;
        top_idx[t * 2]     = i0; top_idx[t * 2 + 1] = i1;
        routw[t * 2]       = w0; routw[t * 2 + 1]   = w1;
        int p0 = atomicAdd(counts + i0, 1);
        int p1 = atomicAdd(counts + i1, 1);
        gdst[tl][0] = (p0 < CAP) ? (i0 * CAP + p0) : -1;
        gdst[tl][1] = (p1 < CAP) ? (i1 * CAP + p1) : -1;
    }
    __syncthreads();

    // gather-write 32 rows (16 tokens x 2 experts) as bf16, 8B stores
    #pragma unroll
    for (int it = 0; it < 16; ++it) {
        int s   = it * 256 + tid;          // 0..4095
        int job = s >> 7, el = s & 127;    // job: (token,k), el: float4 index
        int tl  = job >> 1, k = job & 1;
        int dst = gdst[tl][k];
        if (dst >= 0) {
            float4 v = ((const float4*)(xt + tl * DIM))[el];
            bf16x4 o = { (__bf16)v.x, (__bf16)v.y, (__bf16)v.z, (__bf16)v.w };
            *(bf16x4*)(Xg + (size_t)dst * DIM + el * 4) = o;
        }
    }
}

// ---------------- K2: per (expert, 64-f-tile) x 2 slots, tb-loop ------------
// R0's measured-best staging (46 us: reg-staged X into padded [kg][129][8],
// W1 fp32->bf16 per chunk, 2 barriers/chunk, 25.6 KB LDS) kept VERBATIM.
// Change: grid 3072 (1/3 early-exit) -> 1024 always-useful blocks; block
// (s, tile) loops tb = s, s+2, s+4 while tb*128 < cnt. silu col-sums are
// additive across tb so hs accumulates; one atomicAdd per block at the end.
// All 1024 blocks co-resident (6 blocks/CU possible) -> no dispatch tail.
__global__ __launch_bounds__(256) void k2_expert_ffn(
    const float* __restrict__ w1, const __bf16* __restrict__ Xg,
    const int* __restrict__ counts, const __bf16* __restrict__ zp,
    float* __restrict__ hmean)
{
    __shared__ __align__(16) __bf16 w1s[8 * 65 * 8];    // 8.3 KB [kg][f(+pad)][8]
    __shared__ __align__(16) __bf16 xs[8 * 129 * 8];    // 16.5 KB [kg][t(+pad)][8]
    __shared__ float hred[64][2];

    const int tid  = threadIdx.x;
    const int bid  = blockIdx.x;
    const int s    = bid >> 9;           // slot parity (0/1)
    const int tile = bid & 511;          // tile fast -> consecutive bids spread XCDs
    const int e    = tile & 15;          // expert fast
    const int f0   = (tile >> 4) * 64;
    const int cnt  = min(counts[e], CAP);
    if (s * BT2 >= cnt) return;          // uniform: whole block exits
    const float inv = 1.f / (float)cnt;

    const int wv   = tid >> 6;
    const int lane = tid & 63;
    const int q    = lane >> 4;          // mfma quad
    const int l15  = lane & 15;
    const int fsub = (wv & 1) * 32;
    const int tsub = (wv >> 1) * 64;

    float hs[8];
    #pragma unroll
    for (int i = 0; i < 8; ++i) hs[i] = 0.f;

    for (int tb = s; tb * BT2 < cnt; tb += 2) {
        floatx4 acc[2][4];
        #pragma unroll
        for (int a = 0; a < 2; ++a)
            #pragma unroll
            for (int b = 0; b < 4; ++b) acc[a][b] = (floatx4)0.f;

        for (int c = 0; c < 8; ++c) {        // K chunks of 64
            const int d0 = c * 64;
            __syncthreads();
            // stage W1 tile chunk: 64 f x 64 d, fp32 -> bf16
            #pragma unroll
            for (int it = 0; it < 2; ++it) {
                int ss = it * 256 + tid;
                int f = ss >> 3, g = ss & 7;
                const float* src = w1 + ((size_t)(e * FDIM + f0 + f)) * DIM + d0 + g * 8;
                float4 a = ((const float4*)src)[0];
                float4 b = ((const float4*)src)[1];
                bf16x8 v;
                v[0] = (__bf16)a.x; v[1] = (__bf16)a.y; v[2] = (__bf16)a.z; v[3] = (__bf16)a.w;
                v[4] = (__bf16)b.x; v[5] = (__bf16)b.y; v[6] = (__bf16)b.z; v[7] = (__bf16)b.w;
                *(bf16x8*)(w1s + ((size_t)g * 65 + f) * 8) = v;
            }
            // stage X chunk: 128 t x 64 d (bf16 gathered; pads read zero page)
            {
                const int kg = tid & 7;
                const int r0 = tid >> 3;     // 0..31
                #pragma unroll
                for (int it = 0; it < 4; ++it) {
                    int t = it * 32 + r0;
                    int r = tb * BT2 + t;
                    const __bf16* src = (r < cnt)
                        ? (Xg + ((size_t)(e * CAP + r)) * DIM + d0 + kg * 8)
                        : zp;
                    uint4 d = *(const uint4*)src;
                    *(uint4*)(xs + ((size_t)kg * 129 + t) * 8) = d;
                }
            }
            __syncthreads();
            // 2 K-steps of 32 per chunk
            #pragma unroll
            for (int ks = 0; ks < 2; ++ks) {
                const int kg = ks * 4 + q;
                bf16x8 af0 = *(const bf16x8*)(w1s + (kg * 65 + fsub + l15) * 8);
                bf16x8 af1 = *(const bf16x8*)(w1s + (kg * 65 + fsub + 16 + l15) * 8);
                #pragma unroll
                for (int tt = 0; tt < 4; ++tt) {
                    bf16x8 bfr = *(const bf16x8*)(xs + (kg * 129 + tsub + tt * 16 + l15) * 8);
                    acc[0][tt] = __builtin_amdgcn_mfma_f32_16x16x32_bf16(af0, bfr, acc[0][tt], 0, 0, 0);
                    acc[1][tt] = __builtin_amdgcn_mfma_f32_16x16x32_bf16(af1, bfr, acc[1][tt], 0, 0, 0);
                }
            }
        }

        // silu then column-sum into hs (additive across tb; pads give silu(0)=0)
        #pragma unroll
        for (int fa = 0; fa < 2; ++fa)
            #pragma unroll
            for (int tt = 0; tt < 4; ++tt)
                #pragma unroll
                for (int r = 0; r < 4; ++r) {
                    float v = acc[fa][tt][r];
                    hs[fa * 4 + r] += v / (1.f + __expf(-v));
                }
    }

    // sum over the 16 token-columns held across lanes of each quad
    #pragma unroll
    for (int i = 0; i < 8; ++i) {
        float v = hs[i];
        v += __shfl_xor(v, 1);
        v += __shfl_xor(v, 2);
        v += __shfl_xor(v, 4);
        v += __shfl_xor(v, 8);
        hs[i] = v;
    }
    if (l15 == 0) {
        #pragma unroll
        for (int fa = 0; fa < 2; ++fa)
            #pragma unroll
            for (int r = 0; r < 4; ++r) {
                int row = fsub + fa * 16 + q * 4 + r;
                hred[row][wv >> 1] = hs[fa * 4 + r];
            }
    }
    __syncthreads();
    if (tid < 64)
        atomicAdd(hmean + (size_t)e * FDIM + f0 + tid,
                  (hred[tid][0] + hred[tid][1]) * inv);
}

// ---------------- K3: y_mean[e,d] = h_mean[e,:] . w2[e,d,:]  (fp32) ---------
__global__ __launch_bounds__(256) void k3_ymean(
    const float* __restrict__ w2, const float* __restrict__ hmean,
    const int* __restrict__ counts, float* __restrict__ ymean)
{
    __shared__ float hl[FDIM];           // 8 KB
    const int tid = threadIdx.x;
    const int bid = blockIdx.x;
    const int e   = bid >> 7;
    const int d0  = (bid & 127) * 4;

    {
        const float4* hg = (const float4*)(hmean + (size_t)e * FDIM);
        float4* hl4 = (float4*)hl;
        hl4[tid]       = hg[tid];
        hl4[256 + tid] = hg[256 + tid];
    }
    __syncthreads();

    const int wv = tid >> 6, lane = tid & 63;
    const int d = d0 + wv;
    const float4* wr  = (const float4*)(w2 + ((size_t)e * DIM + d) * FDIM);
    const float4* hl4 = (const float4*)hl;
    float acc = 0.f;
    #pragma unroll
    for (int i = 0; i < 8; ++i) {
        float4 a = wr[i * 64 + lane];
        float4 h = hl4[i * 64 + lane];
        acc += a.x * h.x + a.y * h.y + a.z * h.z + a.w * h.w;
    }
    #pragma unroll
    for (int m = 1; m < 64; m <<= 1) acc += __shfl_xor(acc, m);
    if (lane == 0)
        ymean[e * DIM + d] = (counts[e] > 0) ? acc : 0.f;
}

// ---------------- K4: out[t,:] = w0*y[e0,:] + w1*y[e1,:] --------------------
__global__ __launch_bounds__(256) void k4_combine(
    const int* __restrict__ top_idx, const float* __restrict__ routw,
    const float* __restrict__ ymean, float* __restrict__ out)
{
    const int idx = blockIdx.x * 256 + threadIdx.x;   // float4 index
    const int t = idx >> 7;
    const int c = idx & 127;
    const int i0 = top_idx[t * 2], i1 = top_idx[t * 2 + 1];
    const float w0 = routw[t * 2], w1 = routw[t * 2 + 1];
    float4 a = ((const float4*)(ymean + (size_t)i0 * DIM))[c];
    float4 b = ((const float4*)(ymean + (size_t)i1 * DIM))[c];
    float4 o;
    o.x = w0 * a.x + w1 * b.x;
    o.y = w0 * a.y + w1 * b.y;
    o.z = w0 * a.z + w1 * b.z;
    o.w = w0 * a.w + w1 * b.w;
    ((float4*)out)[idx] = o;
}

extern "C" void kernel_launch(void* const* d_in, const int* in_sizes, int n_in,
                              void* d_out, int out_size, void* d_ws, size_t ws_size,
                              hipStream_t stream)
{
    (void)in_sizes; (void)n_in; (void)out_size; (void)ws_size;
    const float* x  = (const float*)d_in[0];   // [4,512,512]
    const float* gw = (const float*)d_in[1];   // [16,512]
    const float* w1 = (const float*)d_in[2];   // [16,2048,512]
    const float* w2 = (const float*)d_in[3];   // [16,512,2048]
    float* out = (float*)d_out;

    char* ws = (char*)d_ws;
    int*    counts  = (int*)   (ws + WS_COUNTS);
    const __bf16* zp = (const __bf16*)(ws + WS_ZEROPAGE);
    int*    top_idx = (int*)   (ws + WS_TOPIDX);
    float*  routw   = (float*) (ws + WS_ROUTW);
    float*  hmean   = (float*) (ws + WS_HMEAN);
    float*  ymean   = (float*) (ws + WS_YMEAN);
    __bf16* Xg      = (__bf16*)(ws + WS_XG);

    hipMemsetAsync(d_ws, 0, WS_ZERO_BYTES, stream);   // counts + zero page only

    k1_route_gather<<<dim3(NTOK / 16), dim3(256), 0, stream>>>(x, gw, counts, top_idx, routw, Xg, hmean);
    k2_expert_ffn  <<<dim3(2 * 512), dim3(256), 0, stream>>>(w1, Xg, counts, zp, hmean);
    k3_ymean       <<<dim3(NEXP * 128), dim3(256), 0, stream>>>(w2, hmean, counts, ymean);
    k4_combine     <<<dim3(NTOK * DIM / 4 / 256), dim3(256), 0, stream>>>(top_idx, routw, ymean, out);
}

// Round 8
// 212.310 us; speedup vs baseline: 1.2152x; 1.0243x over previous
//
#include <hip/hip_runtime.h>

#define NTOK   2048
#define DIM    512
#define FDIM   2048
#define NEXP   16
#define CAP    768     // max routed tokens buffered per expert (mean ~256)
#define BT2    128     // token block per K2 workgroup
#define NTB    (CAP / BT2)   // 6 token-block slots

typedef __bf16 bf16x8 __attribute__((ext_vector_type(8)));
typedef __bf16 bf16x4 __attribute__((ext_vector_type(4)));
typedef float  floatx4 __attribute__((ext_vector_type(4)));

// workspace layout (bytes)
#define WS_COUNTS    0         // 16 ints (memset 0)
#define WS_ZEROPAGE  1024      // >=1KB zeros for pad-lane loads (memset 0)
#define WS_TOPIDX    4096      // NTOK*2 ints
#define WS_ROUTW     20480     // NTOK*2 floats
#define WS_HMEAN     36864     // NEXP*FDIM floats (zeroed by k1 — atomic accumulated)
#define WS_YMEAN     167936    // NEXP*DIM floats
#define WS_XG        200704    // NEXP*CAP*DIM bf16 = 12.6 MB
#define WS_ZERO_BYTES 2048     // counts + zero page only

// ---------------- K1: gate logits, top-2 softmax, gather x rows (bf16) ------
__global__ __launch_bounds__(256) void k1_route_gather(
    const float* __restrict__ x, const float* __restrict__ gw,
    int* __restrict__ counts, int* __restrict__ top_idx,
    float* __restrict__ routw, __bf16* __restrict__ Xg,
    float* __restrict__ hmean)
{
    __shared__ float xt[16 * DIM];    // 32 KB: 16 token rows
    __shared__ float lg[16][17];
    __shared__ int   gdst[16][2];
    const int tid = threadIdx.x;
    const int t0  = blockIdx.x * 16;

    // zero this block's slice of hmean (32768 floats over 128 blocks x 256 thr)
    hmean[blockIdx.x * 256 + tid] = 0.f;

    {   // stage 16 token rows, coalesced float4
        const float4* src = (const float4*)(x + (size_t)t0 * DIM);
        float4* dst = (float4*)xt;
        #pragma unroll
        for (int i = 0; i < 8; ++i) dst[i * 256 + tid] = src[i * 256 + tid];
    }
    __syncthreads();

    {   // logits: thread = (token tl, expert e)
        const int tl = tid >> 4, e = tid & 15;
        const float4* xr = (const float4*)(xt + tl * DIM);
        const float4* gr = (const float4*)(gw + e * DIM);
        float acc = 0.f;
        #pragma unroll 8
        for (int j = 0; j < DIM / 4; ++j) {
            float4 a = xr[j], b = gr[j];
            acc += a.x * b.x + a.y * b.y + a.z * b.z + a.w * b.w;
        }
        lg[tl][e] = acc;
    }
    __syncthreads();

    if (tid < 16) {   // per-token top-2 + softmax + slot allocation
        const int tl = tid;
        float v0 = -1e30f, v1 = -1e30f; int i0 = 0, i1 = 0;
        #pragma unroll
        for (int e = 0; e < NEXP; ++e) {
            float v = lg[tl][e];
            if (v > v0)      { v1 = v0; i1 = i0; v0 = v; i0 = e; }
            else if (v > v1) { v1 = v;  i1 = e; }
        }
        float e1 = __expf(v1 - v0);          // v0 >= v1
        float w0 = 1.f / (1.f + e1);
        float w1 = 1.f - w0;
        const int t = t0 + tl;
        top_idx[t * 2]     = i0; top_idx[t * 2 + 1] = i1;
        routw[t * 2]       = w0; routw[t * 2 + 1]   = w1;
        int p0 = atomicAdd(counts + i0, 1);
        int p1 = atomicAdd(counts + i1, 1);
        gdst[tl][0] = (p0 < CAP) ? (i0 * CAP + p0) : -1;
        gdst[tl][1] = (p1 < CAP) ? (i1 * CAP + p1) : -1;
    }
    __syncthreads();

    // gather-write 32 rows (16 tokens x 2 experts) as bf16, 8B stores
    #pragma unroll
    for (int it = 0; it < 16; ++it) {
        int s   = it * 256 + tid;          // 0..4095
        int job = s >> 7, el = s & 127;    // job: (token,k), el: float4 index
        int tl  = job >> 1, k = job & 1;
        int dst = gdst[tl][k];
        if (dst >= 0) {
            float4 v = ((const float4*)(xt + tl * DIM))[el];
            bf16x4 o = { (__bf16)v.x, (__bf16)v.y, (__bf16)v.z, (__bf16)v.w };
            *(bf16x4*)(Xg + (size_t)dst * DIM + el * 4) = o;
        }
    }
}

// ---------------- K2: per (expert, 64-f-tile, 128-token-block) --------------
// R0's measured-best structure (46 us) with ONE schedule change: chunk c+1's
// global loads (W1 4xfloat4, X 4xuint4) are issued AFTER chunk c's LDS writes,
// and barrier B is a RAW s_barrier (lgkmcnt(0) only, no vmcnt drain), so the
// loads stay in flight across B + 16 MFMAs + barrier A. The compiler's vmcnt
// wait lands at the next iteration's cvt (after __syncthreads A) -- load
// latency is covered by the MFMA phase instead of sitting naked inside the
// stage phase. Issue-site and use-site are in different basic blocks
// (separated by two barriers), so the scheduler cannot re-fuse them (R4's
// failure mode). Cross-thread safety: barrier A orders prev MFMA reads before
// WRITE's overwrites; lgkmcnt(0)+B orders WRITE's ds_writes before MFMA-phase
// ds_reads; the un-drained vmcnt at B covers only thread-private registers.
// Staging code, LDS layout, grid, epilogue: identical to R0.
__global__ __launch_bounds__(256) void k2_expert_ffn(
    const float* __restrict__ w1, const __bf16* __restrict__ Xg,
    const int* __restrict__ counts, const __bf16* __restrict__ zp,
    float* __restrict__ hmean)
{
    __shared__ __align__(16) __bf16 w1s[8 * 65 * 8];    // 8.3 KB [kg][f(+pad)][8]
    __shared__ __align__(16) __bf16 xs[8 * 129 * 8];    // 16.5 KB [kg][t(+pad)][8]
    __shared__ float hred[64][2];

    const int tid = threadIdx.x;
    const int bid = blockIdx.x;
    const int tb  = bid >> 9;            // slow: token-block (same (e,f) tiles 512 apart)
    const int rem = bid & 511;
    const int e   = rem & 15;            // expert fast
    const int f0  = (rem >> 4) * 64;
    const int cnt = min(counts[e], CAP);
    if (tb * BT2 >= cnt) return;         // inactive slot
    const float inv = 1.f / (float)cnt;

    const int wv   = tid >> 6;
    const int lane = tid & 63;
    const int q    = lane >> 4;          // mfma quad
    const int l15  = lane & 15;
    const int fsub = (wv & 1) * 32;
    const int tsub = (wv >> 1) * 64;

    // W1 staging slots (R0 decomposition): s=tid -> (f,g); s=tid+256 -> (f+32,g)
    const int wfA = tid >> 3, wgA = tid & 7;
    const int wfB = wfA + 32;
    const float* w1pA = w1 + ((size_t)(e * FDIM + f0 + wfA)) * DIM + wgA * 8;
    const float* w1pB = w1 + ((size_t)(e * FDIM + f0 + wfB)) * DIM + wgA * 8;
    // X staging slots (R0 decomposition): kg=tid&7, rows t = it*32 + (tid>>3)
    const int xkg = tid & 7, xr0 = tid >> 3;

    float4 wa0, wb0, wa1, wb1;           // in-flight W1 fp32 (next chunk)
    uint4  xv0, xv1, xv2, xv3;           // in-flight X bf16 rows (next chunk)

    // issue chunk c's global loads into registers (no waits here)
    auto ISSUE = [&](int c) {
        const int d0 = c * 64;
        wa0 = ((const float4*)(w1pA + d0))[0];
        wb0 = ((const float4*)(w1pA + d0))[1];
        wa1 = ((const float4*)(w1pB + d0))[0];
        wb1 = ((const float4*)(w1pB + d0))[1];
        const __bf16* xb = Xg + (size_t)e * CAP * DIM + d0 + xkg * 8;
        int r0 = tb * BT2 + xr0;
        const __bf16* s0 = (r0       < cnt) ? (xb + (size_t)(r0      ) * DIM) : zp;
        const __bf16* s1 = (r0 +  32 < cnt) ? (xb + (size_t)(r0 +  32) * DIM) : zp;
        const __bf16* s2 = (r0 +  64 < cnt) ? (xb + (size_t)(r0 +  64) * DIM) : zp;
        const __bf16* s3 = (r0 +  96 < cnt) ? (xb + (size_t)(r0 +  96) * DIM) : zp;
        xv0 = *(const uint4*)s0;
        xv1 = *(const uint4*)s1;
        xv2 = *(const uint4*)s2;
        xv3 = *(const uint4*)s3;
    };
    // cvt + LDS writes for the chunk whose loads were issued last (R0 layout)
    auto WRITE = [&]() {
        bf16x8 v;
        v[0] = (__bf16)wa0.x; v[1] = (__bf16)wa0.y; v[2] = (__bf16)wa0.z; v[3] = (__bf16)wa0.w;
        v[4] = (__bf16)wb0.x; v[5] = (__bf16)wb0.y; v[6] = (__bf16)wb0.z; v[7] = (__bf16)wb0.w;
        *(bf16x8*)(w1s + ((size_t)wgA * 65 + wfA) * 8) = v;
        v[0] = (__bf16)wa1.x; v[1] = (__bf16)wa1.y; v[2] = (__bf16)wa1.z; v[3] = (__bf16)wa1.w;
        v[4] = (__bf16)wb1.x; v[5] = (__bf16)wb1.y; v[6] = (__bf16)wb1.z; v[7] = (__bf16)wb1.w;
        *(bf16x8*)(w1s + ((size_t)wgA * 65 + wfB) * 8) = v;
        *(uint4*)(xs + ((size_t)xkg * 129 + xr0      ) * 8) = xv0;
        *(uint4*)(xs + ((size_t)xkg * 129 + xr0 +  32) * 8) = xv1;
        *(uint4*)(xs + ((size_t)xkg * 129 + xr0 +  64) * 8) = xv2;
        *(uint4*)(xs + ((size_t)xkg * 129 + xr0 +  96) * 8) = xv3;
    };

    ISSUE(0);                            // prologue: chunk 0 in flight

    floatx4 acc[2][4];
    #pragma unroll
    for (int a = 0; a < 2; ++a)
        #pragma unroll
        for (int b = 0; b < 4; ++b) acc[a][b] = (floatx4)0.f;

    for (int c = 0; c < 8; ++c) {        // K chunks of 64
        __syncthreads();                 // A: prev MFMA done; drains vmcnt -> regs ready
        WRITE();                         // cvt + 6 ds_writes (chunk c)
        if (c < 7) ISSUE(c + 1);         // prefetch next chunk; stays in flight past B
        asm volatile("s_waitcnt lgkmcnt(0)" ::: "memory");
        __builtin_amdgcn_sched_barrier(0);
        __builtin_amdgcn_s_barrier();    // B: raw barrier, NO vmcnt drain
        __builtin_amdgcn_sched_barrier(0);
        // 2 K-steps of 32 per chunk (identical to R0)
        #pragma unroll
        for (int ks = 0; ks < 2; ++ks) {
            const int kg = ks * 4 + q;
            bf16x8 af0 = *(const bf16x8*)(w1s + (kg * 65 + fsub + l15) * 8);
            bf16x8 af1 = *(const bf16x8*)(w1s + (kg * 65 + fsub + 16 + l15) * 8);
            #pragma unroll
            for (int tt = 0; tt < 4; ++tt) {
                bf16x8 bfr = *(const bf16x8*)(xs + (kg * 129 + tsub + tt * 16 + l15) * 8);
                acc[0][tt] = __builtin_amdgcn_mfma_f32_16x16x32_bf16(af0, bfr, acc[0][tt], 0, 0, 0);
                acc[1][tt] = __builtin_amdgcn_mfma_f32_16x16x32_bf16(af1, bfr, acc[1][tt], 0, 0, 0);
            }
        }
    }

    // silu then column-sum (pad cols give silu(0)=0)
    float hs[8];
    #pragma unroll
    for (int i = 0; i < 8; ++i) hs[i] = 0.f;
    #pragma unroll
    for (int fa = 0; fa < 2; ++fa)
        #pragma unroll
        for (int tt = 0; tt < 4; ++tt)
            #pragma unroll
            for (int r = 0; r < 4; ++r) {
                float v = acc[fa][tt][r];
                hs[fa * 4 + r] += v / (1.f + __expf(-v));
            }

    // sum over the 16 token-columns held across lanes of each quad
    #pragma unroll
    for (int i = 0; i < 8; ++i) {
        float v = hs[i];
        v += __shfl_xor(v, 1);
        v += __shfl_xor(v, 2);
        v += __shfl_xor(v, 4);
        v += __shfl_xor(v, 8);
        hs[i] = v;
    }
    if (l15 == 0) {
        #pragma unroll
        for (int fa = 0; fa < 2; ++fa)
            #pragma unroll
            for (int r = 0; r < 4; ++r) {
                int row = fsub + fa * 16 + q * 4 + r;
                hred[row][wv >> 1] = hs[fa * 4 + r];
            }
    }
    __syncthreads();
    if (tid < 64)
        atomicAdd(hmean + (size_t)e * FDIM + f0 + tid,
                  (hred[tid][0] + hred[tid][1]) * inv);
}

// ---------------- K3: y_mean[e,d] = h_mean[e,:] . w2[e,d,:]  (fp32) ---------
__global__ __launch_bounds__(256) void k3_ymean(
    const float* __restrict__ w2, const float* __restrict__ hmean,
    const int* __restrict__ counts, float* __restrict__ ymean)
{
    __shared__ float hl[FDIM];           // 8 KB
    const int tid = threadIdx.x;
    const int bid = blockIdx.x;
    const int e   = bid >> 7;
    const int d0  = (bid & 127) * 4;

    {
        const float4* hg = (const float4*)(hmean + (size_t)e * FDIM);
        float4* hl4 = (float4*)hl;
        hl4[tid]       = hg[tid];
        hl4[256 + tid] = hg[256 + tid];
    }
    __syncthreads();

    const int wv = tid >> 6, lane = tid & 63;
    const int d = d0 + wv;
    const float4* wr  = (const float4*)(w2 + ((size_t)e * DIM + d) * FDIM);
    const float4* hl4 = (const float4*)hl;
    float acc = 0.f;
    #pragma unroll
    for (int i = 0; i < 8; ++i) {
        float4 a = wr[i * 64 + lane];
        float4 h = hl4[i * 64 + lane];
        acc += a.x * h.x + a.y * h.y + a.z * h.z + a.w * h.w;
    }
    #pragma unroll
    for (int m = 1; m < 64; m <<= 1) acc += __shfl_xor(acc, m);
    if (lane == 0)
        ymean[e * DIM + d] = (counts[e] > 0) ? acc : 0.f;
}

// ---------------- K4: out[t,:] = w0*y[e0,:] + w1*y[e1,:] --------------------
__global__ __launch_bounds__(256) void k4_combine(
    const int* __restrict__ top_idx, const float* __restrict__ routw,
    const float* __restrict__ ymean, float* __restrict__ out)
{
    const int idx = blockIdx.x * 256 + threadIdx.x;   // float4 index
    const int t = idx >> 7;
    const int c = idx & 127;
    const int i0 = top_idx[t * 2], i1 = top_idx[t * 2 + 1];
    const float w0 = routw[t * 2], w1 = routw[t * 2 + 1];
    float4 a = ((const float4*)(ymean + (size_t)i0 * DIM))[c];
    float4 b = ((const float4*)(ymean + (size_t)i1 * DIM))[c];
    float4 o;
    o.x = w0 * a.x + w1 * b.x;
    o.y = w0 * a.y + w1 * b.y;
    o.z = w0 * a.z + w1 * b.z;
    o.w = w0 * a.w + w1 * b.w;
    ((float4*)out)[idx] = o;
}

extern "C" void kernel_launch(void* const* d_in, const int* in_sizes, int n_in,
                              void* d_out, int out_size, void* d_ws, size_t ws_size,
                              hipStream_t stream)
{
    (void)in_sizes; (void)n_in; (void)out_size; (void)ws_size;
    const float* x  = (const float*)d_in[0];   // [4,512,512]
    const float* gw = (const float*)d_in[1];   // [16,512]
    const float* w1 = (const float*)d_in[2];   // [16,2048,512]
    const float* w2 = (const float*)d_in[3];   // [16,512,2048]
    float* out = (float*)d_out;

    char* ws = (char*)d_ws;
    int*    counts  = (int*)   (ws + WS_COUNTS);
    const __bf16* zp = (const __bf16*)(ws + WS_ZEROPAGE);
    int*    top_idx = (int*)   (ws + WS_TOPIDX);
    float*  routw   = (float*) (ws + WS_ROUTW);
    float*  hmean   = (float*) (ws + WS_HMEAN);
    float*  ymean   = (float*) (ws + WS_YMEAN);
    __bf16* Xg      = (__bf16*)(ws + WS_XG);

    hipMemsetAsync(d_ws, 0, WS_ZERO_BYTES, stream);   // counts + zero page only

    k1_route_gather<<<dim3(NTOK / 16), dim3(256), 0, stream>>>(x, gw, counts, top_idx, routw, Xg, hmean);
    k2_expert_ffn  <<<dim3(NTB * 32 * NEXP), dim3(256), 0, stream>>>(w1, Xg, counts, zp, hmean);
    k3_ymean       <<<dim3(NEXP * 128), dim3(256), 0, stream>>>(w2, hmean, counts, ymean);
    k4_combine     <<<dim3(NTOK * DIM / 4 / 256), dim3(256), 0, stream>>>(top_idx, routw, ymean, out);
}

// Round 9
// 198.579 us; speedup vs baseline: 1.2992x; 1.0692x over previous
//
#include <hip/hip_runtime.h>

#define NTOK   2048
#define DIM    512
#define FDIM   2048
#define NEXP   16
#define CAP    768     // max routed tokens buffered per expert (mean ~256)
#define BT2    128     // token block per K2 workgroup
#define NTB    (CAP / BT2)   // 6 token-block slots
#define CNTS   32      // counts stride in ints (128 B -> one L2 line per counter)

typedef __bf16 bf16x8 __attribute__((ext_vector_type(8)));
typedef __bf16 bf16x4 __attribute__((ext_vector_type(4)));
typedef float  floatx4 __attribute__((ext_vector_type(4)));

// workspace layout (bytes)
#define WS_COUNTS    0         // 16 counters x 128 B apart (memset 0)
#define WS_ZEROPAGE  2048      // 1KB zeros for pad-lane loads (memset 0)
#define WS_TOPIDX    4096      // NTOK*2 ints
#define WS_ROUTW     20480     // NTOK*2 floats
#define WS_HMEAN     36864     // NEXP*FDIM floats (zeroed by k1 — atomic accumulated)
#define WS_YMEAN     167936    // NEXP*DIM floats
#define WS_XG        200704    // NEXP*CAP*DIM bf16 = 12.6 MB
#define WS_ZERO_BYTES 3072     // counts + zero page

// ---------------- K1: gate logits, top-2 softmax, gather x rows (bf16) ------
// Residue-attack revision: 256 blocks (8 tokens each, 2x latency hiding),
// hierarchical slot allocation (LDS-local ranks + <=16 cacheline-padded
// global atomics per block instead of 4096 same-line device atomics),
// gather stores widened to 16 B.
__global__ __launch_bounds__(256) void k1_route_gather(
    const float* __restrict__ x, const float* __restrict__ gw,
    int* __restrict__ counts, int* __restrict__ top_idx,
    float* __restrict__ routw, __bf16* __restrict__ Xg,
    float* __restrict__ hmean)
{
    __shared__ float xt[8 * DIM];     // 16 KB: 8 token rows
    __shared__ float lg[8][17];
    __shared__ int   cnt_loc[16], base_loc[16];
    __shared__ int   ei[8][2], rk[8][2], gdst[8][2];
    const int tid = threadIdx.x;
    const int t0  = blockIdx.x * 8;

    // zero hmean (32768 floats over 256 blocks x 128 threads)
    if (tid < 128) hmean[blockIdx.x * 128 + tid] = 0.f;
    if (tid < 16)  cnt_loc[tid] = 0;

    {   // stage 8 token rows, coalesced float4
        const float4* src = (const float4*)(x + (size_t)t0 * DIM);
        float4* dst = (float4*)xt;
        #pragma unroll
        for (int i = 0; i < 4; ++i) dst[i * 256 + tid] = src[i * 256 + tid];
    }
    __syncthreads();

    if (tid < 128) {   // logits: thread = (token tl, expert e)
        const int tl = tid >> 4, e = tid & 15;
        const float4* xr = (const float4*)(xt + tl * DIM);
        const float4* gr = (const float4*)(gw + e * DIM);
        float acc = 0.f;
        #pragma unroll 8
        for (int j = 0; j < DIM / 4; ++j) {
            float4 a = xr[j], b = gr[j];
            acc += a.x * b.x + a.y * b.y + a.z * b.z + a.w * b.w;
        }
        lg[tl][e] = acc;
    }
    __syncthreads();

    if (tid < 8) {   // per-token top-2 + softmax + LOCAL rank (LDS atomics)
        const int tl = tid;
        float v0 = -1e30f, v1 = -1e30f; int i0 = 0, i1 = 0;
        #pragma unroll
        for (int e = 0; e < NEXP; ++e) {
            float v = lg[tl][e];
            if (v > v0)      { v1 = v0; i1 = i0; v0 = v; i0 = e; }
            else if (v > v1) { v1 = v;  i1 = e; }
        }
        float e1 = __expf(v1 - v0);          // v0 >= v1
        float w0 = 1.f / (1.f + e1);
        float w1 = 1.f - w0;
        const int t = t0 + tl;
        top_idx[t * 2]     = i0; top_idx[t * 2 + 1] = i1;
        routw[t * 2]       = w0; routw[t * 2 + 1]   = w1;
        ei[tl][0] = i0; ei[tl][1] = i1;
        rk[tl][0] = atomicAdd(&cnt_loc[i0], 1);
        rk[tl][1] = atomicAdd(&cnt_loc[i1], 1);
    }
    __syncthreads();
    if (tid < 16) {  // ONE padded global atomic per (block, expert)
        int n = cnt_loc[tid];
        base_loc[tid] = (n > 0) ? atomicAdd(counts + tid * CNTS, n) : 0;
    }
    __syncthreads();
    if (tid < 8) {   // final slot = global base + local rank
        #pragma unroll
        for (int k = 0; k < 2; ++k) {
            int p = base_loc[ei[tid][k]] + rk[tid][k];
            gdst[tid][k] = (p < CAP) ? (ei[tid][k] * CAP + p) : -1;
        }
    }
    __syncthreads();

    // gather-write 16 rows (8 tokens x 2 experts) as bf16, 16B stores;
    // one wave per job row -> 1 KB contiguous per wave instruction
    #pragma unroll
    for (int it = 0; it < 4; ++it) {
        int s   = it * 256 + tid;          // 0..1023
        int job = s >> 6, el = s & 63;     // job: (token,k), el: 16B chunk
        int tl  = job >> 1, k = job & 1;
        int dst = gdst[tl][k];
        if (dst >= 0) {
            float4 a = ((const float4*)(xt + tl * DIM))[el * 2];
            float4 b = ((const float4*)(xt + tl * DIM))[el * 2 + 1];
            bf16x8 o;
            o[0] = (__bf16)a.x; o[1] = (__bf16)a.y; o[2] = (__bf16)a.z; o[3] = (__bf16)a.w;
            o[4] = (__bf16)b.x; o[5] = (__bf16)b.y; o[6] = (__bf16)b.z; o[7] = (__bf16)b.w;
            *(bf16x8*)(Xg + (size_t)dst * DIM + el * 8) = o;
        }
    }
}

// ---------------- K2: per (expert, 64-f-tile, 128-token-block) --------------
// R0's measured-best k2, verbatim (46 us across 7 structural A/Bs — parked).
// Only change: counts read uses the padded stride.
__global__ __launch_bounds__(256) void k2_expert_ffn(
    const float* __restrict__ w1, const __bf16* __restrict__ Xg,
    const int* __restrict__ counts, const __bf16* __restrict__ zp,
    float* __restrict__ hmean)
{
    __shared__ __align__(16) __bf16 w1s[8 * 65 * 8];    // 8.3 KB [kg][f(+pad)][8]
    __shared__ __align__(16) __bf16 xs[8 * 129 * 8];    // 16.5 KB [kg][t(+pad)][8]
    __shared__ float hred[64][2];

    const int tid = threadIdx.x;
    const int bid = blockIdx.x;
    const int tb  = bid >> 9;            // slow: token-block (same (e,f) tiles 512 apart)
    const int rem = bid & 511;
    const int e   = rem & 15;            // expert fast
    const int f0  = (rem >> 4) * 64;
    const int cnt = min(counts[e * CNTS], CAP);
    if (tb * BT2 >= cnt) return;         // inactive slot
    const float inv = 1.f / (float)cnt;

    const int wv   = tid >> 6;
    const int lane = tid & 63;
    const int q    = lane >> 4;          // mfma quad
    const int l15  = lane & 15;
    const int fsub = (wv & 1) * 32;
    const int tsub = (wv >> 1) * 64;

    floatx4 acc[2][4];
    #pragma unroll
    for (int a = 0; a < 2; ++a)
        #pragma unroll
        for (int b = 0; b < 4; ++b) acc[a][b] = (floatx4)0.f;

    for (int c = 0; c < 8; ++c) {        // K chunks of 64
        const int d0 = c * 64;
        __syncthreads();
        // stage W1 tile chunk: 64 f x 64 d, fp32 -> bf16
        #pragma unroll
        for (int it = 0; it < 2; ++it) {
            int s = it * 256 + tid;
            int f = s >> 3, g = s & 7;
            const float* src = w1 + ((size_t)(e * FDIM + f0 + f)) * DIM + d0 + g * 8;
            float4 a = ((const float4*)src)[0];
            float4 b = ((const float4*)src)[1];
            bf16x8 v;
            v[0] = (__bf16)a.x; v[1] = (__bf16)a.y; v[2] = (__bf16)a.z; v[3] = (__bf16)a.w;
            v[4] = (__bf16)b.x; v[5] = (__bf16)b.y; v[6] = (__bf16)b.z; v[7] = (__bf16)b.w;
            *(bf16x8*)(w1s + ((size_t)g * 65 + f) * 8) = v;
        }
        // stage X chunk: 128 t x 64 d (bf16 gathered; pads read zero page)
        {
            const int kg = tid & 7;
            const int r0 = tid >> 3;     // 0..31
            #pragma unroll
            for (int it = 0; it < 4; ++it) {
                int t = it * 32 + r0;
                int r = tb * BT2 + t;
                const __bf16* src = (r < cnt)
                    ? (Xg + ((size_t)(e * CAP + r)) * DIM + d0 + kg * 8)
                    : zp;
                uint4 d = *(const uint4*)src;
                *(uint4*)(xs + ((size_t)kg * 129 + t) * 8) = d;
            }
        }
        __syncthreads();
        // 2 K-steps of 32 per chunk
        #pragma unroll
        for (int ks = 0; ks < 2; ++ks) {
            const int kg = ks * 4 + q;
            bf16x8 af0 = *(const bf16x8*)(w1s + (kg * 65 + fsub + l15) * 8);
            bf16x8 af1 = *(const bf16x8*)(w1s + (kg * 65 + fsub + 16 + l15) * 8);
            #pragma unroll
            for (int tt = 0; tt < 4; ++tt) {
                bf16x8 bfr = *(const bf16x8*)(xs + (kg * 129 + tsub + tt * 16 + l15) * 8);
                acc[0][tt] = __builtin_amdgcn_mfma_f32_16x16x32_bf16(af0, bfr, acc[0][tt], 0, 0, 0);
                acc[1][tt] = __builtin_amdgcn_mfma_f32_16x16x32_bf16(af1, bfr, acc[1][tt], 0, 0, 0);
            }
        }
    }

    // silu then column-sum (pad cols give silu(0)=0)
    float hs[8];
    #pragma unroll
    for (int i = 0; i < 8; ++i) hs[i] = 0.f;
    #pragma unroll
    for (int fa = 0; fa < 2; ++fa)
        #pragma unroll
        for (int tt = 0; tt < 4; ++tt)
            #pragma unroll
            for (int r = 0; r < 4; ++r) {
                float v = acc[fa][tt][r];
                hs[fa * 4 + r] += v / (1.f + __expf(-v));
            }

    // sum over the 16 token-columns held across lanes of each quad
    #pragma unroll
    for (int i = 0; i < 8; ++i) {
        float v = hs[i];
        v += __shfl_xor(v, 1);
        v += __shfl_xor(v, 2);
        v += __shfl_xor(v, 4);
        v += __shfl_xor(v, 8);
        hs[i] = v;
    }
    if (l15 == 0) {
        #pragma unroll
        for (int fa = 0; fa < 2; ++fa)
            #pragma unroll
            for (int r = 0; r < 4; ++r) {
                int row = fsub + fa * 16 + q * 4 + r;
                hred[row][wv >> 1] = hs[fa * 4 + r];
            }
    }
    __syncthreads();
    if (tid < 64)
        atomicAdd(hmean + (size_t)e * FDIM + f0 + tid,
                  (hred[tid][0] + hred[tid][1]) * inv);
}

// ---------------- K3: y_mean[e,d] = h_mean[e,:] . w2[e,d,:]  (fp32) ---------
__global__ __launch_bounds__(256) void k3_ymean(
    const float* __restrict__ w2, const float* __restrict__ hmean,
    const int* __restrict__ counts, float* __restrict__ ymean)
{
    __shared__ float hl[FDIM];           // 8 KB
    const int tid = threadIdx.x;
    const int bid = blockIdx.x;
    const int e   = bid >> 7;
    const int d0  = (bid & 127) * 4;

    {
        const float4* hg = (const float4*)(hmean + (size_t)e * FDIM);
        float4* hl4 = (float4*)hl;
        hl4[tid]       = hg[tid];
        hl4[256 + tid] = hg[256 + tid];
    }
    __syncthreads();

    const int wv = tid >> 6, lane = tid & 63;
    const int d = d0 + wv;
    const float4* wr  = (const float4*)(w2 + ((size_t)e * DIM + d) * FDIM);
    const float4* hl4 = (const float4*)hl;
    float acc = 0.f;
    #pragma unroll
    for (int i = 0; i < 8; ++i) {
        float4 a = wr[i * 64 + lane];
        float4 h = hl4[i * 64 + lane];
        acc += a.x * h.x + a.y * h.y + a.z * h.z + a.w * h.w;
    }
    #pragma unroll
    for (int m = 1; m < 64; m <<= 1) acc += __shfl_xor(acc, m);
    if (lane == 0)
        ymean[e * DIM + d] = (counts[e * CNTS] > 0) ? acc : 0.f;
}

// ---------------- K4: out[t,:] = w0*y[e0,:] + w1*y[e1,:] --------------------
__global__ __launch_bounds__(256) void k4_combine(
    const int* __restrict__ top_idx, const float* __restrict__ routw,
    const float* __restrict__ ymean, float* __restrict__ out)
{
    const int idx = blockIdx.x * 256 + threadIdx.x;   // float4 index
    const int t = idx >> 7;
    const int c = idx & 127;
    const int i0 = top_idx[t * 2], i1 = top_idx[t * 2 + 1];
    const float w0 = routw[t * 2], w1 = routw[t * 2 + 1];
    float4 a = ((const float4*)(ymean + (size_t)i0 * DIM))[c];
    float4 b = ((const float4*)(ymean + (size_t)i1 * DIM))[c];
    float4 o;
    o.x = w0 * a.x + w1 * b.x;
    o.y = w0 * a.y + w1 * b.y;
    o.z = w0 * a.z + w1 * b.z;
    o.w = w0 * a.w + w1 * b.w;
    ((float4*)out)[idx] = o;
}

extern "C" void kernel_launch(void* const* d_in, const int* in_sizes, int n_in,
                              void* d_out, int out_size, void* d_ws, size_t ws_size,
                              hipStream_t stream)
{
    (void)in_sizes; (void)n_in; (void)out_size; (void)ws_size;
    const float* x  = (const float*)d_in[0];   // [4,512,512]
    const float* gw = (const float*)d_in[1];   // [16,512]
    const float* w1 = (const float*)d_in[2];   // [16,2048,512]
    const float* w2 = (const float*)d_in[3];   // [16,512,2048]
    float* out = (float*)d_out;

    char* ws = (char*)d_ws;
    int*    counts  = (int*)   (ws + WS_COUNTS);
    const __bf16* zp = (const __bf16*)(ws + WS_ZEROPAGE);
    int*    top_idx = (int*)   (ws + WS_TOPIDX);
    float*  routw   = (float*) (ws + WS_ROUTW);
    float*  hmean   = (float*) (ws + WS_HMEAN);
    float*  ymean   = (float*) (ws + WS_YMEAN);
    __bf16* Xg      = (__bf16*)(ws + WS_XG);

    hipMemsetAsync(d_ws, 0, WS_ZERO_BYTES, stream);   // counts + zero page only

    k1_route_gather<<<dim3(NTOK / 8), dim3(256), 0, stream>>>(x, gw, counts, top_idx, routw, Xg, hmean);
    k2_expert_ffn  <<<dim3(NTB * 32 * NEXP), dim3(256), 0, stream>>>(w1, Xg, counts, zp, hmean);
    k3_ymean       <<<dim3(NEXP * 128), dim3(256), 0, stream>>>(w2, hmean, counts, ymean);
    k4_combine     <<<dim3(NTOK * DIM / 4 / 256), dim3(256), 0, stream>>>(top_idx, routw, ymean, out);
}